// Round 14
// baseline (358.939 us; speedup 1.0000x reference)
//
#include <hip/hip_runtime.h>
#include <hip/hip_bf16.h>
#include <math.h>

typedef __hip_bfloat16 bf16;

typedef __bf16 bf16x8 __attribute__((ext_vector_type(8)));
typedef float f32x4 __attribute__((ext_vector_type(4)));
typedef short shortx8 __attribute__((ext_vector_type(8)));

__device__ __forceinline__ float b2f_us(unsigned short u) {
    unsigned int v = ((unsigned int)u) << 16;
    return __builtin_bit_cast(float, v);
}
__device__ __forceinline__ unsigned short f2b_us(float f) {
    return __builtin_bit_cast(unsigned short, __float2bfloat16(f));
}
__device__ __forceinline__ float4 ld4(const float* p) { return *(const float4*)p; }
__device__ __forceinline__ float4 ld4(const bf16* p) {
    ushort4 u = *(const ushort4*)p;
    return make_float4(b2f_us(u.x), b2f_us(u.y), b2f_us(u.z), b2f_us(u.w));
}
__device__ __forceinline__ bf16x8 ldfrag(const bf16* p) {
    return __builtin_bit_cast(bf16x8, *(const shortx8*)p);
}
__device__ __forceinline__ f32x4 mfma16(bf16x8 a, bf16x8 b, f32x4 c) {
    return __builtin_amdgcn_mfma_f32_16x16x32_bf16(a, b, c, 0, 0, 0);
}
__device__ __forceinline__ void gload16(const bf16* g, bf16* l) {
    __builtin_amdgcn_global_load_lds(
        (const __attribute__((address_space(1))) void*)g,
        (__attribute__((address_space(3))) void*)l, 16, 0, 0);
}
// tanh-form GELU via sigmoid: 0.5g(1+tanh(0.79788456(g+0.044715 g^3)))
//                            = g * sigmoid(1.5957691(g+0.044715 g^3))
__device__ __forceinline__ float gelu_fast(float g) {
    float g2 = g * g;
    float y = -1.5957691f * (g + 0.044715f * g * g2);
    return g / (1.f + __expf(y));
}

// ---------------------------------------------------------------- batched weight convert
struct WJob { const float* src; bf16* dst; int R, C, tile0, trans; };
struct WJobs { WJob j[8]; };

__global__ __launch_bounds__(256) void wconv_all(WJobs jobs) {
    __shared__ float tl[32][33];
    int bid = blockIdx.x;
    int ji = 0;
#pragma unroll
    for (int i = 1; i < 8; ++i)
        if (bid >= jobs.j[i].tile0) ji = i;
    WJob jb = jobs.j[ji];
    int t = bid - jb.tile0;
    int tc = jb.C >> 5;
    int tr_ = t / tc, tcx = t - tr_ * tc;
    int r0 = tr_ * 32, c0 = tcx * 32;
    const int tx = threadIdx.x & 31, ty = threadIdx.x >> 5;
    if (jb.trans) {
#pragma unroll
        for (int i = 0; i < 4; ++i)
            tl[ty + i * 8][tx] = jb.src[(long)(r0 + ty + i * 8) * jb.C + c0 + tx];
        __syncthreads();
#pragma unroll
        for (int i = 0; i < 4; ++i)
            jb.dst[(long)(c0 + ty + i * 8) * jb.R + r0 + tx] =
                __float2bfloat16(tl[tx][ty + i * 8]);
    } else {
#pragma unroll
        for (int i = 0; i < 4; ++i) {
            long idx = (long)(r0 + ty + i * 8) * jb.C + c0 + tx;
            jb.dst[idx] = __float2bfloat16(jb.src[idx]);
        }
    }
}

// ---------------------------------------------------------------- GN stats
__global__ __launch_bounds__(256) void gn_stats_k(const float* __restrict__ x,
                                                  float* __restrict__ stats) {
    int bg = blockIdx.x;
    long base = (long)bg * 16384;
    int tid = threadIdx.x;
    float s = 0.f, sq = 0.f;
    for (int it = 0; it < 16; ++it) {
        float4 v = *(const float4*)(x + base + (long)it * 1024 + tid * 4);
        s += v.x + v.y + v.z + v.w;
        sq += v.x * v.x + v.y * v.y + v.z * v.z + v.w * v.w;
    }
#pragma unroll
    for (int off = 32; off; off >>= 1) {
        s += __shfl_down(s, off);
        sq += __shfl_down(sq, off);
    }
    __shared__ float r0[4], r1[4];
    if ((tid & 63) == 0) { r0[tid >> 6] = s; r1[tid >> 6] = sq; }
    __syncthreads();
    if (tid == 0) {
        s = r0[0] + r0[1] + r0[2] + r0[3];
        sq = r1[0] + r1[1] + r1[2] + r1[3];
        float mu = s * (1.f / 16384.f);
        float var = sq * (1.f / 16384.f) - mu * mu;
        stats[bg] = mu;
        stats[256 + bg] = rsqrtf(var + 1e-6f);
    }
}

// ---------------------------------------------------------------- GN + transpose + bf16
__global__ __launch_bounds__(256) void gnxt_k(const float* __restrict__ x,
                                              const float* __restrict__ stats,
                                              const float* __restrict__ gng,
                                              const float* __restrict__ gnb,
                                              bf16* __restrict__ xt) {
    const int b = blockIdx.z;
    const int c0 = blockIdx.y * 64, s0 = blockIdx.x * 64;
    __shared__ float t[64][65];
    const int tx = threadIdx.x & 15, ty = threadIdx.x >> 4;
#pragma unroll
    for (int i = 0; i < 4; ++i) {
        int c = c0 + ty + i * 16;
        float rs = stats[256 + b * 32 + (c >> 4)];
        float ga = gng[c] * rs;
        float be = gnb[c] - stats[b * 32 + (c >> 4)] * ga;
        float4 v = *(const float4*)(x + ((long)b * 512 + c) * 1024 + s0 + tx * 4);
        t[ty + i * 16][tx * 4 + 0] = v.x * ga + be;
        t[ty + i * 16][tx * 4 + 1] = v.y * ga + be;
        t[ty + i * 16][tx * 4 + 2] = v.z * ga + be;
        t[ty + i * 16][tx * 4 + 3] = v.w * ga + be;
    }
    __syncthreads();
#pragma unroll
    for (int i = 0; i < 4; ++i) {
        int s = s0 + ty + i * 16;
        ushort4 o;
        o.x = f2b_us(t[tx * 4 + 0][ty + i * 16]);
        o.y = f2b_us(t[tx * 4 + 1][ty + i * 16]);
        o.z = f2b_us(t[tx * 4 + 2][ty + i * 16]);
        o.w = f2b_us(t[tx * 4 + 3][ty + i * 16]);
        *(ushort4*)(xt + ((long)b * 1024 + s) * 512 + c0 + tx * 4) = o;
    }
}

// ---------------------------------------------------------------- LayerNorm (wave-per-row, vectorized)
__global__ __launch_bounds__(256) void ln_k(const bf16* __restrict__ in,
                                            const float* __restrict__ g,
                                            const float* __restrict__ bvec,
                                            bf16* __restrict__ out) {
    const int wave = threadIdx.x >> 6, lane = threadIdx.x & 63;
    const long row = (long)blockIdx.x * 4 + wave;
    const bf16* p = in + row * 512 + lane * 8;
    shortx8 raw = *(const shortx8*)p;
    float v[8];
    float s = 0.f, sq = 0.f;
#pragma unroll
    for (int j = 0; j < 8; ++j) {
        v[j] = b2f_us((unsigned short)raw[j]);
        s += v[j];
        sq += v[j] * v[j];
    }
#pragma unroll
    for (int off = 32; off; off >>= 1) {
        s += __shfl_xor(s, off);
        sq += __shfl_xor(sq, off);
    }
    float mu = s * (1.f / 512.f);
    float var = sq * (1.f / 512.f) - mu * mu;
    float rs = rsqrtf(var + 1e-5f);
    float4 g0 = *(const float4*)(g + lane * 8);
    float4 g1 = *(const float4*)(g + lane * 8 + 4);
    float4 b0 = *(const float4*)(bvec + lane * 8);
    float4 b1 = *(const float4*)(bvec + lane * 8 + 4);
    float gv[8] = {g0.x, g0.y, g0.z, g0.w, g1.x, g1.y, g1.z, g1.w};
    float bv[8] = {b0.x, b0.y, b0.z, b0.w, b1.x, b1.y, b1.z, b1.w};
    shortx8 o;
#pragma unroll
    for (int j = 0; j < 8; ++j)
        o[j] = __builtin_bit_cast(short,
            f2b_us((v[j] - mu) * rs * gv[j] + bv[j]));
    *(shortx8*)(out + row * 512 + lane * 8) = o;
}

// ---------------------------------------------------------------- 256x128 MFMA GEMM, 8 waves, 2-barrier loop
// VSPLIT: n0>=1024 columns are V -> write transposed to vtout.
template <bool HASBIAS, bool HASRES, bool VSPLIT>
__global__ __launch_bounds__(512, 4) void mm256_k(
    const bf16* __restrict__ A, const bf16* __restrict__ Bw,
    const float* __restrict__ bias, const bf16* __restrict__ res,
    bf16* __restrict__ C, bf16* __restrict__ vtout,
    int lda, int ldb, int ldc, int NT) {
    __shared__ bf16 sA[16384];   // 256 x 64, 32 subtiles
    __shared__ bf16 sB[8192];    // 128 x 64, 16 subtiles
    const int lane = threadIdx.x & 63, wave = threadIdx.x >> 6;  // 0..7
    const int lr = lane & 15, lg = lane >> 4;
    const int wm = wave >> 1, wn = wave & 1;                     // 4M x 2N
    const int m0 = blockIdx.x * 256, n0 = blockIdx.y * 128;

    f32x4 acc[4][4];
#pragma unroll
    for (int i = 0; i < 4; ++i)
#pragma unroll
        for (int j = 0; j < 4; ++j) acc[i][j] = (f32x4){0.f, 0.f, 0.f, 0.f};

    for (int t = 0; t < NT; ++t) {
        const int k0 = t * 64;
#pragma unroll
        for (int q = 0; q < 4; ++q) {
            int st = wave * 4 + q;            // 0..31
            int kh = st >> 4, sm = st & 15;
            gload16(A + (long)(m0 + sm * 16 + lr) * lda + k0 + kh * 32 + lg * 8,
                    &sA[st << 9]);
        }
#pragma unroll
        for (int q = 0; q < 2; ++q) {
            int bs = wave * 2 + q;            // 0..15
            int kh = bs >> 3, sn = bs & 7;
            gload16(Bw + (long)(n0 + sn * 16 + lr) * ldb + k0 + kh * 32 + lg * 8,
                    &sB[bs << 9]);
        }
        asm volatile("s_waitcnt vmcnt(0) lgkmcnt(0)" ::: "memory");
        __builtin_amdgcn_s_barrier();
#pragma unroll
        for (int kh = 0; kh < 2; ++kh) {
            bf16x8 af[4], bfr[4];
#pragma unroll
            for (int i = 0; i < 4; ++i)
                af[i] = ldfrag(&sA[((kh * 16 + wm * 4 + i) << 9) + lane * 8]);
#pragma unroll
            for (int j = 0; j < 4; ++j)
                bfr[j] = ldfrag(&sB[((kh * 8 + wn * 4 + j) << 9) + lane * 8]);
#pragma unroll
            for (int i = 0; i < 4; ++i)
#pragma unroll
                for (int j = 0; j < 4; ++j)
                    acc[i][j] = mfma16(af[i], bfr[j], acc[i][j]);
        }
        __builtin_amdgcn_s_barrier();
    }

    if (VSPLIT && n0 >= 1024) {
#pragma unroll
        for (int i = 0; i < 4; ++i) {
            int row = m0 + wm * 64 + i * 16 + lg * 4;
            int bb = row >> 10, ss = row & 1023;
#pragma unroll
            for (int j = 0; j < 4; ++j) {
                int col = n0 + wn * 64 + j * 16 + lr;
                int v = col - 1024;
                int hh = v >> 6, dd = v & 63;
                ushort4 o4;
                o4.x = f2b_us(acc[i][j][0]);
                o4.y = f2b_us(acc[i][j][1]);
                o4.z = f2b_us(acc[i][j][2]);
                o4.w = f2b_us(acc[i][j][3]);
                *(ushort4*)(vtout + ((long)(bb * 8 + hh) * 64 + dd) * 1024 + ss) = o4;
            }
        }
        return;
    }
#pragma unroll
    for (int i = 0; i < 4; ++i) {
        int row = m0 + wm * 64 + i * 16 + lg * 4;
#pragma unroll
        for (int j = 0; j < 4; ++j) {
            int col = n0 + wn * 64 + j * 16 + lr;
            float bv = HASBIAS ? bias[col] : 0.f;
#pragma unroll
            for (int r = 0; r < 4; ++r) {
                float v = acc[i][j][r] + bv;
                if (HASRES)
                    v += b2f_us(__builtin_bit_cast(unsigned short,
                             res[(long)(row + r) * ldc + col]));
                C[(long)(row + r) * ldc + col] = __float2bfloat16(v);
            }
        }
    }
}

// ---------------------------------------------------------------- 256x128out GEGLU GEMM, 8 waves (2M x 4N)
// B tile = 128 val rows + 128 gate rows; wave owns 128 rows x 32 cols (val+gate).
__global__ __launch_bounds__(512, 1) void mm256_geglu_k(
    const bf16* __restrict__ A, const bf16* __restrict__ Bv,
    const bf16* __restrict__ Bg, const float* __restrict__ bias,
    bf16* __restrict__ C, int NT) {
    __shared__ bf16 sA[16384];   // 256 x 64, 32 subtiles
    __shared__ bf16 sB[16384];   // (128 val + 128 gate) x 64, 32 subtiles
    const int lane = threadIdx.x & 63, wave = threadIdx.x >> 6;
    const int lr = lane & 15, lg = lane >> 4;
    const int wm = wave >> 2, wn = wave & 3;   // 2M x 4N
    const int m0 = blockIdx.x * 256, n0 = blockIdx.y * 128;

    f32x4 accv[8][2], accg[8][2];
#pragma unroll
    for (int i = 0; i < 8; ++i)
#pragma unroll
        for (int j = 0; j < 2; ++j) {
            accv[i][j] = (f32x4){0.f, 0.f, 0.f, 0.f};
            accg[i][j] = (f32x4){0.f, 0.f, 0.f, 0.f};
        }

    for (int t = 0; t < NT; ++t) {
        const int k0 = t * 64;
#pragma unroll
        for (int q = 0; q < 4; ++q) {
            int st = wave * 4 + q;            // 0..31 A subtiles
            int kh = st >> 4, sm = st & 15;
            gload16(A + (long)(m0 + sm * 16 + lr) * 512 + k0 + kh * 32 + lg * 8,
                    &sA[st << 9]);
        }
#pragma unroll
        for (int q = 0; q < 4; ++q) {
            int f = wave * 4 + q;             // 0..31 B subtiles
            int half = f >> 4, r = f & 15;    // half 0=val 1=gate
            int kh = r >> 3, sn = r & 7;
            const bf16* bsrc = half ? Bg : Bv;
            gload16(bsrc + (long)(n0 + sn * 16 + lr) * 512 + k0 + kh * 32 + lg * 8,
                    &sB[f << 9]);
        }
        asm volatile("s_waitcnt vmcnt(0) lgkmcnt(0)" ::: "memory");
        __builtin_amdgcn_s_barrier();
#pragma unroll
        for (int kh = 0; kh < 2; ++kh) {
            bf16x8 bv_[2], bg_[2];
#pragma unroll
            for (int j = 0; j < 2; ++j) {
                bv_[j] = ldfrag(&sB[((kh * 8 + wn * 2 + j) << 9) + lane * 8]);
                bg_[j] = ldfrag(&sB[((16 + kh * 8 + wn * 2 + j) << 9) + lane * 8]);
            }
#pragma unroll
            for (int i = 0; i < 8; ++i) {
                bf16x8 af = ldfrag(&sA[((kh * 16 + wm * 8 + i) << 9) + lane * 8]);
#pragma unroll
                for (int j = 0; j < 2; ++j) {
                    accv[i][j] = mfma16(af, bv_[j], accv[i][j]);
                    accg[i][j] = mfma16(af, bg_[j], accg[i][j]);
                }
            }
        }
        __builtin_amdgcn_s_barrier();
    }

#pragma unroll
    for (int i = 0; i < 8; ++i) {
        int row = m0 + wm * 128 + i * 16 + lg * 4;
#pragma unroll
        for (int j = 0; j < 2; ++j) {
            int col = n0 + (wn * 2 + j) * 16 + lr;
            float bv = bias[col], bg2 = bias[2048 + col];
#pragma unroll
            for (int r = 0; r < 4; ++r) {
                float v = accv[i][j][r] + bv;
                float g = accg[i][j][r] + bg2;
                C[(long)(row + r) * 2048 + col] = __float2bfloat16(v * gelu_fast(g));
            }
        }
    }
}

// ---------------------------------------------------------------- MFMA GEMM, single-buf 2-barrier loop (N=512 path)
template <bool HASBIAS, bool HASRES, int BN>
__global__ __launch_bounds__(256, 4) void mm_k(
    const bf16* __restrict__ A, const bf16* __restrict__ Bw,
    const float* __restrict__ bias, const bf16* __restrict__ res,
    bf16* __restrict__ C, int lda, int ldb, int ldc, int NT) {
    constexpr int NJ = BN / 64 * 2;
    __shared__ bf16 sA[8192];
    __shared__ bf16 sB[BN == 128 ? 8192 : 4096];
    const int lane = threadIdx.x & 63, wave = threadIdx.x >> 6;
    const int lr = lane & 15, lg = lane >> 4;
    const int wm = wave >> 1, wn = wave & 1;
    const int m0 = blockIdx.y * 128, n0 = blockIdx.x * BN;

    f32x4 acc[4][NJ];
#pragma unroll
    for (int i = 0; i < 4; ++i)
#pragma unroll
        for (int j = 0; j < NJ; ++j) acc[i][j] = (f32x4){0.f, 0.f, 0.f, 0.f};

    for (int t = 0; t < NT; ++t) {
        const int k0 = t * 64;
#pragma unroll
        for (int q = 0; q < 4; ++q) {
            int st = wave * 4 + q;
            int kh = st >> 3, sm = st & 7;
            gload16(A + (long)(m0 + sm * 16 + lr) * lda + k0 + kh * 32 + lg * 8,
                    &sA[st << 9]);
        }
        if (BN == 128) {
#pragma unroll
            for (int q = 0; q < 4; ++q) {
                int st = wave * 4 + q;
                int kh = st >> 3, sn = st & 7;
                gload16(Bw + (long)(n0 + sn * 16 + lr) * ldb + k0 + kh * 32 + lg * 8,
                        &sB[st << 9]);
            }
        } else {
#pragma unroll
            for (int q = 0; q < 2; ++q) {
                int bs = wave * 2 + q;
                int kh = bs >> 2, sn = bs & 3;
                gload16(Bw + (long)(n0 + sn * 16 + lr) * ldb + k0 + kh * 32 + lg * 8,
                        &sB[bs << 9]);
            }
        }
        asm volatile("s_waitcnt vmcnt(0) lgkmcnt(0)" ::: "memory");
        __builtin_amdgcn_s_barrier();
#pragma unroll
        for (int kh = 0; kh < 2; ++kh) {
            bf16x8 af[4], bfr[NJ];
#pragma unroll
            for (int i = 0; i < 4; ++i)
                af[i] = ldfrag(&sA[((kh * 8 + wm * 4 + i) << 9) + lane * 8]);
#pragma unroll
            for (int j = 0; j < NJ; ++j) {
                int bs = BN == 128 ? (kh * 8 + wn * 4 + j) : (kh * 4 + wn * 2 + j);
                bfr[j] = ldfrag(&sB[(bs << 9) + lane * 8]);
            }
#pragma unroll
            for (int i = 0; i < 4; ++i)
#pragma unroll
                for (int j = 0; j < NJ; ++j)
                    acc[i][j] = mfma16(af[i], bfr[j], acc[i][j]);
        }
        __builtin_amdgcn_s_barrier();
    }

#pragma unroll
    for (int i = 0; i < 4; ++i) {
        int row = m0 + wm * 64 + i * 16 + lg * 4;
#pragma unroll
        for (int j = 0; j < NJ; ++j) {
            int col = n0 + wn * (BN / 2) + j * 16 + lr;
            float bv = HASBIAS ? bias[col] : 0.f;
#pragma unroll
            for (int r = 0; r < 4; ++r) {
                float v = acc[i][j][r] + bv;
                if (HASRES)
                    v += b2f_us(__builtin_bit_cast(unsigned short,
                             res[(long)(row + r) * ldc + col]));
                C[(long)(row + r) * ldc + col] = __float2bfloat16(v);
            }
        }
    }
}

// ---------------------------------------------------------------- conv_out GEMM with fused transpose+bias+residual
__global__ __launch_bounds__(256, 4) void mm_convout_k(
    const bf16* __restrict__ A, const bf16* __restrict__ Bw,
    const float* __restrict__ bias, const float* __restrict__ xres,
    float* __restrict__ Co, int NT) {
    __shared__ bf16 sA[8192];
    __shared__ bf16 sB[4096];
    const int lane = threadIdx.x & 63, wave = threadIdx.x >> 6;
    const int lr = lane & 15, lg = lane >> 4;
    const int wm = wave >> 1, wn = wave & 1;
    const int m0 = blockIdx.y * 128, n0 = blockIdx.x * 64;

    f32x4 acc[4][2];
#pragma unroll
    for (int i = 0; i < 4; ++i)
#pragma unroll
        for (int j = 0; j < 2; ++j) acc[i][j] = (f32x4){0.f, 0.f, 0.f, 0.f};

    for (int t = 0; t < NT; ++t) {
        const int k0 = t * 64;
#pragma unroll
        for (int q = 0; q < 4; ++q) {
            int st = wave * 4 + q;
            int kh = st >> 3, sm = st & 7;
            gload16(A + (long)(m0 + sm * 16 + lr) * 512 + k0 + kh * 32 + lg * 8,
                    &sA[st << 9]);
        }
#pragma unroll
        for (int q = 0; q < 2; ++q) {
            int bs = wave * 2 + q;
            int kh = bs >> 2, sn = bs & 3;
            gload16(Bw + (long)(n0 + sn * 16 + lr) * 512 + k0 + kh * 32 + lg * 8,
                    &sB[bs << 9]);
        }
        asm volatile("s_waitcnt vmcnt(0) lgkmcnt(0)" ::: "memory");
        __builtin_amdgcn_s_barrier();
#pragma unroll
        for (int kh = 0; kh < 2; ++kh) {
            bf16x8 af[4], bfr[2];
#pragma unroll
            for (int i = 0; i < 4; ++i)
                af[i] = ldfrag(&sA[((kh * 8 + wm * 4 + i) << 9) + lane * 8]);
#pragma unroll
            for (int j = 0; j < 2; ++j)
                bfr[j] = ldfrag(&sB[((kh * 4 + wn * 2 + j) << 9) + lane * 8]);
#pragma unroll
            for (int i = 0; i < 4; ++i)
#pragma unroll
                for (int j = 0; j < 2; ++j)
                    acc[i][j] = mfma16(af[i], bfr[j], acc[i][j]);
        }
        __builtin_amdgcn_s_barrier();
    }

#pragma unroll
    for (int i = 0; i < 4; ++i) {
        int row = m0 + wm * 64 + i * 16 + lg * 4;
        int bb = row >> 10, ss = row & 1023;
#pragma unroll
        for (int j = 0; j < 2; ++j) {
            int col = n0 + wn * 32 + j * 16 + lr;
            long idx = ((long)bb * 512 + col) * 1024 + ss;
            float4 xr = *(const float4*)(xres + idx);
            float bc = bias[col];
            float4 w;
            w.x = acc[i][j][0] + bc + xr.x;
            w.y = acc[i][j][1] + bc + xr.y;
            w.z = acc[i][j][2] + bc + xr.z;
            w.w = acc[i][j][3] + bc + xr.w;
            *(float4*)(Co + idx) = w;
        }
    }
}

// ---------------------------------------------------------------- MFMA flash attention
__global__ __launch_bounds__(256) void attn_mfma_k(const bf16* __restrict__ qkv,
                                                   const bf16* __restrict__ vt,
                                                   bf16* __restrict__ o) {
    const int wave = threadIdx.x >> 6, lane = threadIdx.x & 63;
    const int lr = lane & 15, lg = lane >> 4;
    const int h = blockIdx.y, b = blockIdx.z;
    const int q0 = blockIdx.x * 128 + wave * 32;
    __shared__ bf16 sKV[16384];
    __shared__ bf16 plds[4][16][72];
    bf16* pl = &plds[wave][0][0];
    const bf16* qbase = qkv + (long)b * 1024 * 1536 + h * 64;
    const bf16* kbase = qbase + 512;
    const bf16* vbase = vt + ((long)(b * 8 + h) * 64) * 1024;

    bf16x8 qf[2][2];
#pragma unroll
    for (int s = 0; s < 2; ++s) {
        const bf16* qp = qbase + (long)(q0 + s * 16 + lr) * 1536 + lg * 8;
#pragma unroll
        for (int c = 0; c < 2; ++c) {
            shortx8 raw = *(const shortx8*)(qp + c * 32);
            shortx8 sc;
#pragma unroll
            for (int j = 0; j < 8; ++j)
                sc[j] = __builtin_bit_cast(short,
                    f2b_us(b2f_us((unsigned short)raw[j]) * 0.125f));
            qf[s][c] = __builtin_bit_cast(bf16x8, sc);
        }
    }

    f32x4 of[2][4];
    float mrow[2][4], lrow[2][4];
#pragma unroll
    for (int s = 0; s < 2; ++s)
#pragma unroll
        for (int r = 0; r < 4; ++r) {
            of[s][r] = (f32x4){0.f, 0.f, 0.f, 0.f};
            mrow[s][r] = -1e30f;
            lrow[s][r] = 0.f;
        }

    auto computeKV = [&](const bf16* base) {
        f32x4 sf[2][4];
        __builtin_amdgcn_s_setprio(1);
#pragma unroll
        for (int kt = 0; kt < 4; ++kt) {
            bf16x8 k0f = ldfrag(base + (kt * 2) * 512 + lane * 8);
            bf16x8 k1f = ldfrag(base + (kt * 2 + 1) * 512 + lane * 8);
#pragma unroll
            for (int s = 0; s < 2; ++s) {
                f32x4 z = {0.f, 0.f, 0.f, 0.f};
                z = mfma16(qf[s][0], k0f, z);
                z = mfma16(qf[s][1], k1f, z);
                sf[s][kt] = z;
            }
        }
        __builtin_amdgcn_s_setprio(0);

        bf16x8 pa[2][2];
#pragma unroll
        for (int s = 0; s < 2; ++s) {
            float mtl[4];
#pragma unroll
            for (int r = 0; r < 4; ++r)
                mtl[r] = fmaxf(fmaxf(sf[s][0][r], sf[s][1][r]),
                               fmaxf(sf[s][2][r], sf[s][3][r]));
            float need = fmaxf(fmaxf(mtl[0] - mrow[s][0], mtl[1] - mrow[s][1]),
                               fmaxf(mtl[2] - mrow[s][2], mtl[3] - mrow[s][3]));
            if (!__all(need <= 8.f)) {
#pragma unroll
                for (int m = 1; m < 16; m <<= 1)
#pragma unroll
                    for (int r = 0; r < 4; ++r)
                        mtl[r] = fmaxf(mtl[r], __shfl_xor(mtl[r], m));
#pragma unroll
                for (int r = 0; r < 4; ++r) {
                    float mn = fmaxf(mrow[s][r], mtl[r]);
                    float al = __expf(mrow[s][r] - mn);
                    mrow[s][r] = mn;
                    lrow[s][r] *= al;
#pragma unroll
                    for (int dt = 0; dt < 4; ++dt) of[s][dt][r] *= al;
                }
            }
#pragma unroll
            for (int kt = 0; kt < 4; ++kt)
#pragma unroll
                for (int r = 0; r < 4; ++r) {
                    float p = __expf(sf[s][kt][r] - mrow[s][r]);
                    lrow[s][r] += p;
                    pl[(lg * 4 + r) * 72 + kt * 16 + lr] = __float2bfloat16(p);
                }
            pa[s][0] = ldfrag(pl + lr * 72 + lg * 8);
            pa[s][1] = ldfrag(pl + lr * 72 + 32 + lg * 8);
        }
        __builtin_amdgcn_s_setprio(1);
#pragma unroll
        for (int dt = 0; dt < 4; ++dt) {
            bf16x8 v0f = ldfrag(base + (8 + dt * 2) * 512 + lane * 8);
            bf16x8 v1f = ldfrag(base + (8 + dt * 2 + 1) * 512 + lane * 8);
#pragma unroll
            for (int s = 0; s < 2; ++s) {
                of[s][dt] = mfma16(pa[s][0], v0f, of[s][dt]);
                of[s][dt] = mfma16(pa[s][1], v1f, of[s][dt]);
            }
        }
        __builtin_amdgcn_s_setprio(0);
    };

    for (int t = 0; t < 8; ++t) {
        const int kv0 = t * 128;
#pragma unroll
        for (int q = 0; q < 8; ++q) {
            int st = wave * 8 + q;
            int chunk = st >> 4, r = st & 15;
            int kvb = kv0 + chunk * 64;
            const bf16* src;
            if (r < 8)
                src = kbase + (long)(kvb + (r >> 1) * 16 + lr) * 1536 +
                      (r & 1) * 32 + lg * 8;
            else {
                int vs = r - 8;
                src = vbase + (long)((vs >> 1) * 16 + lr) * 1024 + kvb +
                      (vs & 1) * 32 + lg * 8;
            }
            gload16(src, &sKV[st << 9]);
        }
        asm volatile("s_waitcnt vmcnt(0) lgkmcnt(0)" ::: "memory");
        __builtin_amdgcn_s_barrier();
        computeKV(&sKV[0]);
        computeKV(&sKV[8192]);
        __builtin_amdgcn_s_barrier();
    }

#pragma unroll
    for (int s = 0; s < 2; ++s) {
#pragma unroll
        for (int m = 1; m < 16; m <<= 1)
#pragma unroll
            for (int r = 0; r < 4; ++r)
                lrow[s][r] += __shfl_xor(lrow[s][r], m);
        bf16* op = o + ((long)b * 1024 + q0 + s * 16 + lg * 4) * 512 + h * 64 + lr;
#pragma unroll
        for (int r = 0; r < 4; ++r) {
            float inv = 1.f / lrow[s][r];
#pragma unroll
            for (int dt = 0; dt < 4; ++dt)
                op[(long)r * 512 + dt * 16] = __float2bfloat16(of[s][dt][r] * inv);
        }
    }
}

// ---------------------------------------------------------------- launcher
extern "C" void kernel_launch(void* const* d_in, const int* in_sizes, int n_in,
                              void* d_out, int out_size, void* d_ws, size_t ws_size,
                              hipStream_t stream) {
    const float* x = (const float*)d_in[0];
    const float* gn_g = (const float*)d_in[1];
    const float* gn_b = (const float*)d_in[2];
    const float* w_cin = (const float*)d_in[3];
    const float* b_cin = (const float*)d_in[4];
    const float* ln1_g = (const float*)d_in[5];
    const float* ln1_b = (const float*)d_in[6];
    const float* qkv1w = (const float*)d_in[7];
    const float* out1_w = (const float*)d_in[8];
    const float* out1_b = (const float*)d_in[9];
    const float* ln2_g = (const float*)d_in[10];
    const float* ln2_b = (const float*)d_in[11];
    const float* qkv2w = (const float*)d_in[12];
    const float* out2_w = (const float*)d_in[13];
    const float* out2_b = (const float*)d_in[14];
    const float* ln3_g = (const float*)d_in[15];
    const float* ln3_b = (const float*)d_in[16];
    const float* g1_w = (const float*)d_in[17];
    const float* g1_b = (const float*)d_in[18];
    const float* g2_w = (const float*)d_in[19];
    const float* g2_b = (const float*)d_in[20];
    const float* w_cout = (const float*)d_in[21];
    const float* b_cout = (const float*)d_in[22];
    float* out = (float*)d_out;

    char* ws = (char*)d_ws;
    float* stats = (float*)ws;
    bf16* wq1 = (bf16*)(ws + 4096);          // (1536,512)
    bf16* wo1 = wq1 + 1536 * 512;            // (512,512)
    bf16* wq2 = wo1 + 512 * 512;             // (1536,512)
    bf16* wo2 = wq2 + 1536 * 512;            // (512,512)
    bf16* wg1 = wo2 + 512 * 512;             // (4096,512)
    bf16* wg2 = wg1 + 4096 * 512;            // (512,2048)
    bf16* wci = wg2 + 512 * 2048;            // (512,512)
    bf16* wco = wci + 512 * 512;             // (512,512)
    bf16* h = wco + 512 * 512;               // (8192,512)
    bf16* h2 = h + (size_t)8192 * 512;
    bf16* lnb = h2 + (size_t)8192 * 512;     // xt / LN out / attn-O
    bf16* qkv = lnb + (size_t)8192 * 512;    // (8192,1536)
    bf16* obuf = qkv + (size_t)8192 * 1536;  // vt (B,H,64,S) during attn phases
    bf16* gg = qkv;                          // (8192,2048) reuses qkv+obuf
    bf16* vt = obuf;

    WJobs jobs;
    jobs.j[0] = {qkv1w, wq1, 512, 1536, 0, 1};
    jobs.j[1] = {out1_w, wo1, 512, 512, 768, 1};
    jobs.j[2] = {qkv2w, wq2, 512, 1536, 1024, 1};
    jobs.j[3] = {out2_w, wo2, 512, 512, 1792, 1};
    jobs.j[4] = {g1_w, wg1, 512, 4096, 2048, 1};
    jobs.j[5] = {g2_w, wg2, 2048, 512, 4096, 1};
    jobs.j[6] = {w_cin, wci, 512, 512, 5120, 0};
    jobs.j[7] = {w_cout, wco, 512, 512, 5376, 0};
    wconv_all<<<5632, 256, 0, stream>>>(jobs);

    gn_stats_k<<<256, 256, 0, stream>>>(x, stats);
    gnxt_k<<<dim3(16, 8, 8), 256, 0, stream>>>(x, stats, gn_g, gn_b, lnb);
    // conv_in: h = gn(x)^T @ wci^T
    mm_k<true, false, 64><<<dim3(8, 64), 256, 0, stream>>>(
        lnb, wci, b_cin, nullptr, h, 512, 512, 512, 8);

    ln_k<<<2048, 256, 0, stream>>>(h, ln1_g, ln1_b, lnb);
    mm256_k<false, false, true><<<dim3(32, 12), 512, 0, stream>>>(
        lnb, wq1, nullptr, nullptr, qkv, vt, 512, 512, 1536, 8);
    attn_mfma_k<<<dim3(8, 8, 8), 256, 0, stream>>>(qkv, vt, lnb);
    mm_k<true, true, 64><<<dim3(8, 64), 256, 0, stream>>>(
        lnb, wo1, out1_b, h, h2, 512, 512, 512, 8);

    ln_k<<<2048, 256, 0, stream>>>(h2, ln2_g, ln2_b, lnb);
    mm256_k<false, false, true><<<dim3(32, 12), 512, 0, stream>>>(
        lnb, wq2, nullptr, nullptr, qkv, vt, 512, 512, 1536, 8);
    attn_mfma_k<<<dim3(8, 8, 8), 256, 0, stream>>>(qkv, vt, lnb);
    mm_k<true, true, 64><<<dim3(8, 64), 256, 0, stream>>>(
        lnb, wo2, out2_b, h2, h, 512, 512, 512, 8);

    ln_k<<<2048, 256, 0, stream>>>(h, ln3_g, ln3_b, lnb);
    mm256_geglu_k<<<dim3(32, 16), 512, 0, stream>>>(
        lnb, wg1, wg1 + (size_t)2048 * 512, g1_b, gg, 8);
    mm_k<true, true, 64><<<dim3(8, 64), 256, 0, stream>>>(
        gg, wg2, g2_b, h, h2, 2048, 2048, 512, 32);

    // conv_out fused: out[b][o][s] = h2 @ wco^T + b_cout + x
    mm_convout_k<<<dim3(8, 64), 256, 0, stream>>>(
        h2, wco, b_cout, x, out, 8);
}

// Round 15
// 350.659 us; speedup vs baseline: 1.0236x; 1.0236x over previous
//
#include <hip/hip_runtime.h>
#include <hip/hip_bf16.h>
#include <math.h>

typedef __hip_bfloat16 bf16;

typedef __bf16 bf16x8 __attribute__((ext_vector_type(8)));
typedef float f32x4 __attribute__((ext_vector_type(4)));
typedef short shortx8 __attribute__((ext_vector_type(8)));

__device__ __forceinline__ float b2f_us(unsigned short u) {
    unsigned int v = ((unsigned int)u) << 16;
    return __builtin_bit_cast(float, v);
}
__device__ __forceinline__ unsigned short f2b_us(float f) {
    return __builtin_bit_cast(unsigned short, __float2bfloat16(f));
}
__device__ __forceinline__ float4 ld4(const float* p) { return *(const float4*)p; }
__device__ __forceinline__ float4 ld4(const bf16* p) {
    ushort4 u = *(const ushort4*)p;
    return make_float4(b2f_us(u.x), b2f_us(u.y), b2f_us(u.z), b2f_us(u.w));
}
__device__ __forceinline__ bf16x8 ldfrag(const bf16* p) {
    return __builtin_bit_cast(bf16x8, *(const shortx8*)p);
}
__device__ __forceinline__ f32x4 mfma16(bf16x8 a, bf16x8 b, f32x4 c) {
    return __builtin_amdgcn_mfma_f32_16x16x32_bf16(a, b, c, 0, 0, 0);
}
__device__ __forceinline__ void gload16(const bf16* g, bf16* l) {
    __builtin_amdgcn_global_load_lds(
        (const __attribute__((address_space(1))) void*)g,
        (__attribute__((address_space(3))) void*)l, 16, 0, 0);
}
// tanh-form GELU via sigmoid: g * sigmoid(1.5957691(g+0.044715 g^3))
__device__ __forceinline__ float gelu_fast(float g) {
    float g2 = g * g;
    float y = -1.5957691f * (g + 0.044715f * g * g2);
    return g / (1.f + __expf(y));
}

// ---------------------------------------------------------------- batched weight convert
struct WJob { const float* src; bf16* dst; int R, C, tile0, trans; };
struct WJobs { WJob j[8]; };

__global__ __launch_bounds__(256) void wconv_all(WJobs jobs) {
    __shared__ float tl[32][33];
    int bid = blockIdx.x;
    int ji = 0;
#pragma unroll
    for (int i = 1; i < 8; ++i)
        if (bid >= jobs.j[i].tile0) ji = i;
    WJob jb = jobs.j[ji];
    int t = bid - jb.tile0;
    int tc = jb.C >> 5;
    int tr_ = t / tc, tcx = t - tr_ * tc;
    int r0 = tr_ * 32, c0 = tcx * 32;
    const int tx = threadIdx.x & 31, ty = threadIdx.x >> 5;
    if (jb.trans) {
#pragma unroll
        for (int i = 0; i < 4; ++i)
            tl[ty + i * 8][tx] = jb.src[(long)(r0 + ty + i * 8) * jb.C + c0 + tx];
        __syncthreads();
#pragma unroll
        for (int i = 0; i < 4; ++i)
            jb.dst[(long)(c0 + ty + i * 8) * jb.R + r0 + tx] =
                __float2bfloat16(tl[tx][ty + i * 8]);
    } else {
#pragma unroll
        for (int i = 0; i < 4; ++i) {
            long idx = (long)(r0 + ty + i * 8) * jb.C + c0 + tx;
            jb.dst[idx] = __float2bfloat16(jb.src[idx]);
        }
    }
}

// ---------------------------------------------------------------- GN stats
__global__ __launch_bounds__(256) void gn_stats_k(const float* __restrict__ x,
                                                  float* __restrict__ stats) {
    int bg = blockIdx.x;
    long base = (long)bg * 16384;
    int tid = threadIdx.x;
    float s = 0.f, sq = 0.f;
    for (int it = 0; it < 16; ++it) {
        float4 v = *(const float4*)(x + base + (long)it * 1024 + tid * 4);
        s += v.x + v.y + v.z + v.w;
        sq += v.x * v.x + v.y * v.y + v.z * v.z + v.w * v.w;
    }
#pragma unroll
    for (int off = 32; off; off >>= 1) {
        s += __shfl_down(s, off);
        sq += __shfl_down(sq, off);
    }
    __shared__ float r0[4], r1[4];
    if ((tid & 63) == 0) { r0[tid >> 6] = s; r1[tid >> 6] = sq; }
    __syncthreads();
    if (tid == 0) {
        s = r0[0] + r0[1] + r0[2] + r0[3];
        sq = r1[0] + r1[1] + r1[2] + r1[3];
        float mu = s * (1.f / 16384.f);
        float var = sq * (1.f / 16384.f) - mu * mu;
        stats[bg] = mu;
        stats[256 + bg] = rsqrtf(var + 1e-6f);
    }
}

// ---------------------------------------------------------------- GN + transpose + bf16
__global__ __launch_bounds__(256) void gnxt_k(const float* __restrict__ x,
                                              const float* __restrict__ stats,
                                              const float* __restrict__ gng,
                                              const float* __restrict__ gnb,
                                              bf16* __restrict__ xt) {
    const int b = blockIdx.z;
    const int c0 = blockIdx.y * 64, s0 = blockIdx.x * 64;
    __shared__ float t[64][65];
    const int tx = threadIdx.x & 15, ty = threadIdx.x >> 4;
#pragma unroll
    for (int i = 0; i < 4; ++i) {
        int c = c0 + ty + i * 16;
        float rs = stats[256 + b * 32 + (c >> 4)];
        float ga = gng[c] * rs;
        float be = gnb[c] - stats[b * 32 + (c >> 4)] * ga;
        float4 v = *(const float4*)(x + ((long)b * 512 + c) * 1024 + s0 + tx * 4);
        t[ty + i * 16][tx * 4 + 0] = v.x * ga + be;
        t[ty + i * 16][tx * 4 + 1] = v.y * ga + be;
        t[ty + i * 16][tx * 4 + 2] = v.z * ga + be;
        t[ty + i * 16][tx * 4 + 3] = v.w * ga + be;
    }
    __syncthreads();
#pragma unroll
    for (int i = 0; i < 4; ++i) {
        int s = s0 + ty + i * 16;
        ushort4 o;
        o.x = f2b_us(t[tx * 4 + 0][ty + i * 16]);
        o.y = f2b_us(t[tx * 4 + 1][ty + i * 16]);
        o.z = f2b_us(t[tx * 4 + 2][ty + i * 16]);
        o.w = f2b_us(t[tx * 4 + 3][ty + i * 16]);
        *(ushort4*)(xt + ((long)b * 1024 + s) * 512 + c0 + tx * 4) = o;
    }
}

// ---------------------------------------------------------------- LayerNorm (wave-per-row, vectorized)
__global__ __launch_bounds__(256) void ln_k(const bf16* __restrict__ in,
                                            const float* __restrict__ g,
                                            const float* __restrict__ bvec,
                                            bf16* __restrict__ out) {
    const int wave = threadIdx.x >> 6, lane = threadIdx.x & 63;
    const long row = (long)blockIdx.x * 4 + wave;
    const bf16* p = in + row * 512 + lane * 8;
    shortx8 raw = *(const shortx8*)p;
    float v[8];
    float s = 0.f, sq = 0.f;
#pragma unroll
    for (int j = 0; j < 8; ++j) {
        v[j] = b2f_us((unsigned short)raw[j]);
        s += v[j];
        sq += v[j] * v[j];
    }
#pragma unroll
    for (int off = 32; off; off >>= 1) {
        s += __shfl_xor(s, off);
        sq += __shfl_xor(sq, off);
    }
    float mu = s * (1.f / 512.f);
    float var = sq * (1.f / 512.f) - mu * mu;
    float rs = rsqrtf(var + 1e-5f);
    float4 g0 = *(const float4*)(g + lane * 8);
    float4 g1 = *(const float4*)(g + lane * 8 + 4);
    float4 b0 = *(const float4*)(bvec + lane * 8);
    float4 b1 = *(const float4*)(bvec + lane * 8 + 4);
    float gv[8] = {g0.x, g0.y, g0.z, g0.w, g1.x, g1.y, g1.z, g1.w};
    float bv[8] = {b0.x, b0.y, b0.z, b0.w, b1.x, b1.y, b1.z, b1.w};
    shortx8 o;
#pragma unroll
    for (int j = 0; j < 8; ++j)
        o[j] = __builtin_bit_cast(short,
            f2b_us((v[j] - mu) * rs * gv[j] + bv[j]));
    *(shortx8*)(out + row * 512 + lane * 8) = o;
}

// ---------------------------------------------------------------- 256x128 MFMA GEMM, 8 waves, 2-barrier loop
// VSPLIT: n0>=1024 columns are V -> write transposed to vtout.
template <bool HASBIAS, bool HASRES, bool VSPLIT>
__global__ __launch_bounds__(512, 4) void mm256_k(
    const bf16* __restrict__ A, const bf16* __restrict__ Bw,
    const float* __restrict__ bias, const bf16* __restrict__ res,
    bf16* __restrict__ C, bf16* __restrict__ vtout,
    int lda, int ldb, int ldc, int NT) {
    __shared__ bf16 sA[16384];   // 256 x 64, 32 subtiles
    __shared__ bf16 sB[8192];    // 128 x 64, 16 subtiles
    const int lane = threadIdx.x & 63, wave = threadIdx.x >> 6;  // 0..7
    const int lr = lane & 15, lg = lane >> 4;
    const int wm = wave >> 1, wn = wave & 1;                     // 4M x 2N
    const int m0 = blockIdx.x * 256, n0 = blockIdx.y * 128;

    f32x4 acc[4][4];
#pragma unroll
    for (int i = 0; i < 4; ++i)
#pragma unroll
        for (int j = 0; j < 4; ++j) acc[i][j] = (f32x4){0.f, 0.f, 0.f, 0.f};

    for (int t = 0; t < NT; ++t) {
        const int k0 = t * 64;
#pragma unroll
        for (int q = 0; q < 4; ++q) {
            int st = wave * 4 + q;            // 0..31
            int kh = st >> 4, sm = st & 15;
            gload16(A + (long)(m0 + sm * 16 + lr) * lda + k0 + kh * 32 + lg * 8,
                    &sA[st << 9]);
        }
#pragma unroll
        for (int q = 0; q < 2; ++q) {
            int bs = wave * 2 + q;            // 0..15
            int kh = bs >> 3, sn = bs & 7;
            gload16(Bw + (long)(n0 + sn * 16 + lr) * ldb + k0 + kh * 32 + lg * 8,
                    &sB[bs << 9]);
        }
        asm volatile("s_waitcnt vmcnt(0) lgkmcnt(0)" ::: "memory");
        __builtin_amdgcn_s_barrier();
#pragma unroll
        for (int kh = 0; kh < 2; ++kh) {
            bf16x8 af[4], bfr[4];
#pragma unroll
            for (int i = 0; i < 4; ++i)
                af[i] = ldfrag(&sA[((kh * 16 + wm * 4 + i) << 9) + lane * 8]);
#pragma unroll
            for (int j = 0; j < 4; ++j)
                bfr[j] = ldfrag(&sB[((kh * 8 + wn * 4 + j) << 9) + lane * 8]);
#pragma unroll
            for (int i = 0; i < 4; ++i)
#pragma unroll
                for (int j = 0; j < 4; ++j)
                    acc[i][j] = mfma16(af[i], bfr[j], acc[i][j]);
        }
        __builtin_amdgcn_s_barrier();
    }

    if (VSPLIT && n0 >= 1024) {
#pragma unroll
        for (int i = 0; i < 4; ++i) {
            int row = m0 + wm * 64 + i * 16 + lg * 4;
            int bb = row >> 10, ss = row & 1023;
#pragma unroll
            for (int j = 0; j < 4; ++j) {
                int col = n0 + wn * 64 + j * 16 + lr;
                int v = col - 1024;
                int hh = v >> 6, dd = v & 63;
                ushort4 o4;
                o4.x = f2b_us(acc[i][j][0]);
                o4.y = f2b_us(acc[i][j][1]);
                o4.z = f2b_us(acc[i][j][2]);
                o4.w = f2b_us(acc[i][j][3]);
                *(ushort4*)(vtout + ((long)(bb * 8 + hh) * 64 + dd) * 1024 + ss) = o4;
            }
        }
        return;
    }
#pragma unroll
    for (int i = 0; i < 4; ++i) {
        int row = m0 + wm * 64 + i * 16 + lg * 4;
#pragma unroll
        for (int j = 0; j < 4; ++j) {
            int col = n0 + wn * 64 + j * 16 + lr;
            float bv = HASBIAS ? bias[col] : 0.f;
#pragma unroll
            for (int r = 0; r < 4; ++r) {
                float v = acc[i][j][r] + bv;
                if (HASRES)
                    v += b2f_us(__builtin_bit_cast(unsigned short,
                             res[(long)(row + r) * ldc + col]));
                C[(long)(row + r) * ldc + col] = __float2bfloat16(v);
            }
        }
    }
}

// ---------------------------------------------------------------- 256x64 MFMA GEGLU GEMM, 8 waves (r12 geometry + fast GELU)
__global__ __launch_bounds__(512, 4) void mm256_geglu_k(
    const bf16* __restrict__ A, const bf16* __restrict__ Bv,
    const bf16* __restrict__ Bg, const float* __restrict__ bias,
    bf16* __restrict__ C, int NT) {
    __shared__ bf16 sA[16384];   // 256 x 64
    __shared__ bf16 sB[8192];    // (64 val + 64 gate) x 64
    const int lane = threadIdx.x & 63, wave = threadIdx.x >> 6;
    const int lr = lane & 15, lg = lane >> 4;
    const int wm = wave >> 1, wn = wave & 1;
    const int m0 = blockIdx.x * 256, n0 = blockIdx.y * 64;

    f32x4 accv[4][2], accg[4][2];
#pragma unroll
    for (int i = 0; i < 4; ++i)
#pragma unroll
        for (int j = 0; j < 2; ++j) {
            accv[i][j] = (f32x4){0.f, 0.f, 0.f, 0.f};
            accg[i][j] = (f32x4){0.f, 0.f, 0.f, 0.f};
        }

    for (int t = 0; t < NT; ++t) {
        const int k0 = t * 64;
#pragma unroll
        for (int q = 0; q < 4; ++q) {
            int st = wave * 4 + q;
            int kh = st >> 4, sm = st & 15;
            gload16(A + (long)(m0 + sm * 16 + lr) * 512 + k0 + kh * 32 + lg * 8,
                    &sA[st << 9]);
        }
#pragma unroll
        for (int q = 0; q < 2; ++q) {
            int f = wave * 2 + q;             // 0..15
            int kh = f >> 3, r = f & 7;
            const bf16* bsrc = (r < 4) ? Bv : Bg;
            int sn = r & 3;
            gload16(bsrc + (long)(n0 + sn * 16 + lr) * 512 + k0 + kh * 32 + lg * 8,
                    &sB[f << 9]);
        }
        asm volatile("s_waitcnt vmcnt(0) lgkmcnt(0)" ::: "memory");
        __builtin_amdgcn_s_barrier();
#pragma unroll
        for (int kh = 0; kh < 2; ++kh) {
            bf16x8 af[4], bv_[2], bg_[2];
#pragma unroll
            for (int i = 0; i < 4; ++i)
                af[i] = ldfrag(&sA[((kh * 16 + wm * 4 + i) << 9) + lane * 8]);
#pragma unroll
            for (int j = 0; j < 2; ++j) {
                bv_[j] = ldfrag(&sB[((kh * 8 + wn * 2 + j) << 9) + lane * 8]);
                bg_[j] = ldfrag(&sB[((kh * 8 + 4 + wn * 2 + j) << 9) + lane * 8]);
            }
#pragma unroll
            for (int i = 0; i < 4; ++i)
#pragma unroll
                for (int j = 0; j < 2; ++j) {
                    accv[i][j] = mfma16(af[i], bv_[j], accv[i][j]);
                    accg[i][j] = mfma16(af[i], bg_[j], accg[i][j]);
                }
        }
        __builtin_amdgcn_s_barrier();
    }

#pragma unroll
    for (int i = 0; i < 4; ++i) {
        int row = m0 + wm * 64 + i * 16 + lg * 4;
#pragma unroll
        for (int j = 0; j < 2; ++j) {
            int col = n0 + (wn * 2 + j) * 16 + lr;
            float bv = bias[col], bg2 = bias[2048 + col];
#pragma unroll
            for (int r = 0; r < 4; ++r) {
                float v = accv[i][j][r] + bv;
                float g = accg[i][j][r] + bg2;
                C[(long)(row + r) * 2048 + col] = __float2bfloat16(v * gelu_fast(g));
            }
        }
    }
}

// ---------------------------------------------------------------- MFMA GEMM, single-buf 2-barrier loop (N=512 path)
template <bool HASBIAS, bool HASRES, int BN>
__global__ __launch_bounds__(256, 4) void mm_k(
    const bf16* __restrict__ A, const bf16* __restrict__ Bw,
    const float* __restrict__ bias, const bf16* __restrict__ res,
    bf16* __restrict__ C, int lda, int ldb, int ldc, int NT) {
    constexpr int NJ = BN / 64 * 2;
    __shared__ bf16 sA[8192];
    __shared__ bf16 sB[BN == 128 ? 8192 : 4096];
    const int lane = threadIdx.x & 63, wave = threadIdx.x >> 6;
    const int lr = lane & 15, lg = lane >> 4;
    const int wm = wave >> 1, wn = wave & 1;
    const int m0 = blockIdx.y * 128, n0 = blockIdx.x * BN;

    f32x4 acc[4][NJ];
#pragma unroll
    for (int i = 0; i < 4; ++i)
#pragma unroll
        for (int j = 0; j < NJ; ++j) acc[i][j] = (f32x4){0.f, 0.f, 0.f, 0.f};

    for (int t = 0; t < NT; ++t) {
        const int k0 = t * 64;
#pragma unroll
        for (int q = 0; q < 4; ++q) {
            int st = wave * 4 + q;
            int kh = st >> 3, sm = st & 7;
            gload16(A + (long)(m0 + sm * 16 + lr) * lda + k0 + kh * 32 + lg * 8,
                    &sA[st << 9]);
        }
        if (BN == 128) {
#pragma unroll
            for (int q = 0; q < 4; ++q) {
                int st = wave * 4 + q;
                int kh = st >> 3, sn = st & 7;
                gload16(Bw + (long)(n0 + sn * 16 + lr) * ldb + k0 + kh * 32 + lg * 8,
                        &sB[st << 9]);
            }
        } else {
#pragma unroll
            for (int q = 0; q < 2; ++q) {
                int bs = wave * 2 + q;
                int kh = bs >> 2, sn = bs & 3;
                gload16(Bw + (long)(n0 + sn * 16 + lr) * ldb + k0 + kh * 32 + lg * 8,
                        &sB[bs << 9]);
            }
        }
        asm volatile("s_waitcnt vmcnt(0) lgkmcnt(0)" ::: "memory");
        __builtin_amdgcn_s_barrier();
#pragma unroll
        for (int kh = 0; kh < 2; ++kh) {
            bf16x8 af[4], bfr[NJ];
#pragma unroll
            for (int i = 0; i < 4; ++i)
                af[i] = ldfrag(&sA[((kh * 8 + wm * 4 + i) << 9) + lane * 8]);
#pragma unroll
            for (int j = 0; j < NJ; ++j) {
                int bs = BN == 128 ? (kh * 8 + wn * 4 + j) : (kh * 4 + wn * 2 + j);
                bfr[j] = ldfrag(&sB[(bs << 9) + lane * 8]);
            }
#pragma unroll
            for (int i = 0; i < 4; ++i)
#pragma unroll
                for (int j = 0; j < NJ; ++j)
                    acc[i][j] = mfma16(af[i], bfr[j], acc[i][j]);
        }
        __builtin_amdgcn_s_barrier();
    }

#pragma unroll
    for (int i = 0; i < 4; ++i) {
        int row = m0 + wm * 64 + i * 16 + lg * 4;
#pragma unroll
        for (int j = 0; j < NJ; ++j) {
            int col = n0 + wn * (BN / 2) + j * 16 + lr;
            float bv = HASBIAS ? bias[col] : 0.f;
#pragma unroll
            for (int r = 0; r < 4; ++r) {
                float v = acc[i][j][r] + bv;
                if (HASRES)
                    v += b2f_us(__builtin_bit_cast(unsigned short,
                             res[(long)(row + r) * ldc + col]));
                C[(long)(row + r) * ldc + col] = __float2bfloat16(v);
            }
        }
    }
}

// ---------------------------------------------------------------- conv_out GEMM with fused transpose+bias+residual
__global__ __launch_bounds__(256, 4) void mm_convout_k(
    const bf16* __restrict__ A, const bf16* __restrict__ Bw,
    const float* __restrict__ bias, const float* __restrict__ xres,
    float* __restrict__ Co, int NT) {
    __shared__ bf16 sA[8192];
    __shared__ bf16 sB[4096];
    const int lane = threadIdx.x & 63, wave = threadIdx.x >> 6;
    const int lr = lane & 15, lg = lane >> 4;
    const int wm = wave >> 1, wn = wave & 1;
    const int m0 = blockIdx.y * 128, n0 = blockIdx.x * 64;

    f32x4 acc[4][2];
#pragma unroll
    for (int i = 0; i < 4; ++i)
#pragma unroll
        for (int j = 0; j < 2; ++j) acc[i][j] = (f32x4){0.f, 0.f, 0.f, 0.f};

    for (int t = 0; t < NT; ++t) {
        const int k0 = t * 64;
#pragma unroll
        for (int q = 0; q < 4; ++q) {
            int st = wave * 4 + q;
            int kh = st >> 3, sm = st & 7;
            gload16(A + (long)(m0 + sm * 16 + lr) * 512 + k0 + kh * 32 + lg * 8,
                    &sA[st << 9]);
        }
#pragma unroll
        for (int q = 0; q < 2; ++q) {
            int bs = wave * 2 + q;
            int kh = bs >> 2, sn = bs & 3;
            gload16(Bw + (long)(n0 + sn * 16 + lr) * 512 + k0 + kh * 32 + lg * 8,
                    &sB[bs << 9]);
        }
        asm volatile("s_waitcnt vmcnt(0) lgkmcnt(0)" ::: "memory");
        __builtin_amdgcn_s_barrier();
#pragma unroll
        for (int kh = 0; kh < 2; ++kh) {
            bf16x8 af[4], bfr[2];
#pragma unroll
            for (int i = 0; i < 4; ++i)
                af[i] = ldfrag(&sA[((kh * 8 + wm * 4 + i) << 9) + lane * 8]);
#pragma unroll
            for (int j = 0; j < 2; ++j)
                bfr[j] = ldfrag(&sB[((kh * 4 + wn * 2 + j) << 9) + lane * 8]);
#pragma unroll
            for (int i = 0; i < 4; ++i)
#pragma unroll
                for (int j = 0; j < 2; ++j)
                    acc[i][j] = mfma16(af[i], bfr[j], acc[i][j]);
        }
        __builtin_amdgcn_s_barrier();
    }

#pragma unroll
    for (int i = 0; i < 4; ++i) {
        int row = m0 + wm * 64 + i * 16 + lg * 4;
        int bb = row >> 10, ss = row & 1023;
#pragma unroll
        for (int j = 0; j < 2; ++j) {
            int col = n0 + wn * 32 + j * 16 + lr;
            long idx = ((long)bb * 512 + col) * 1024 + ss;
            float4 xr = *(const float4*)(xres + idx);
            float bc = bias[col];
            float4 w;
            w.x = acc[i][j][0] + bc + xr.x;
            w.y = acc[i][j][1] + bc + xr.y;
            w.z = acc[i][j][2] + bc + xr.z;
            w.w = acc[i][j][3] + bc + xr.w;
            *(float4*)(Co + idx) = w;
        }
    }
}

// ---------------------------------------------------------------- MFMA flash attention
__global__ __launch_bounds__(256) void attn_mfma_k(const bf16* __restrict__ qkv,
                                                   const bf16* __restrict__ vt,
                                                   bf16* __restrict__ o) {
    const int wave = threadIdx.x >> 6, lane = threadIdx.x & 63;
    const int lr = lane & 15, lg = lane >> 4;
    const int h = blockIdx.y, b = blockIdx.z;
    const int q0 = blockIdx.x * 128 + wave * 32;
    __shared__ bf16 sKV[16384];
    __shared__ bf16 plds[4][16][72];
    bf16* pl = &plds[wave][0][0];
    const bf16* qbase = qkv + (long)b * 1024 * 1536 + h * 64;
    const bf16* kbase = qbase + 512;
    const bf16* vbase = vt + ((long)(b * 8 + h) * 64) * 1024;

    bf16x8 qf[2][2];
#pragma unroll
    for (int s = 0; s < 2; ++s) {
        const bf16* qp = qbase + (long)(q0 + s * 16 + lr) * 1536 + lg * 8;
#pragma unroll
        for (int c = 0; c < 2; ++c) {
            shortx8 raw = *(const shortx8*)(qp + c * 32);
            shortx8 sc;
#pragma unroll
            for (int j = 0; j < 8; ++j)
                sc[j] = __builtin_bit_cast(short,
                    f2b_us(b2f_us((unsigned short)raw[j]) * 0.125f));
            qf[s][c] = __builtin_bit_cast(bf16x8, sc);
        }
    }

    f32x4 of[2][4];
    float mrow[2][4], lrow[2][4];
#pragma unroll
    for (int s = 0; s < 2; ++s)
#pragma unroll
        for (int r = 0; r < 4; ++r) {
            of[s][r] = (f32x4){0.f, 0.f, 0.f, 0.f};
            mrow[s][r] = -1e30f;
            lrow[s][r] = 0.f;
        }

    auto computeKV = [&](const bf16* base) {
        f32x4 sf[2][4];
        __builtin_amdgcn_s_setprio(1);
#pragma unroll
        for (int kt = 0; kt < 4; ++kt) {
            bf16x8 k0f = ldfrag(base + (kt * 2) * 512 + lane * 8);
            bf16x8 k1f = ldfrag(base + (kt * 2 + 1) * 512 + lane * 8);
#pragma unroll
            for (int s = 0; s < 2; ++s) {
                f32x4 z = {0.f, 0.f, 0.f, 0.f};
                z = mfma16(qf[s][0], k0f, z);
                z = mfma16(qf[s][1], k1f, z);
                sf[s][kt] = z;
            }
        }
        __builtin_amdgcn_s_setprio(0);

        bf16x8 pa[2][2];
#pragma unroll
        for (int s = 0; s < 2; ++s) {
            float mtl[4];
#pragma unroll
            for (int r = 0; r < 4; ++r)
                mtl[r] = fmaxf(fmaxf(sf[s][0][r], sf[s][1][r]),
                               fmaxf(sf[s][2][r], sf[s][3][r]));
            float need = fmaxf(fmaxf(mtl[0] - mrow[s][0], mtl[1] - mrow[s][1]),
                               fmaxf(mtl[2] - mrow[s][2], mtl[3] - mrow[s][3]));
            if (!__all(need <= 8.f)) {
#pragma unroll
                for (int m = 1; m < 16; m <<= 1)
#pragma unroll
                    for (int r = 0; r < 4; ++r)
                        mtl[r] = fmaxf(mtl[r], __shfl_xor(mtl[r], m));
#pragma unroll
                for (int r = 0; r < 4; ++r) {
                    float mn = fmaxf(mrow[s][r], mtl[r]);
                    float al = __expf(mrow[s][r] - mn);
                    mrow[s][r] = mn;
                    lrow[s][r] *= al;
#pragma unroll
                    for (int dt = 0; dt < 4; ++dt) of[s][dt][r] *= al;
                }
            }
#pragma unroll
            for (int kt = 0; kt < 4; ++kt)
#pragma unroll
                for (int r = 0; r < 4; ++r) {
                    float p = __expf(sf[s][kt][r] - mrow[s][r]);
                    lrow[s][r] += p;
                    pl[(lg * 4 + r) * 72 + kt * 16 + lr] = __float2bfloat16(p);
                }
            pa[s][0] = ldfrag(pl + lr * 72 + lg * 8);
            pa[s][1] = ldfrag(pl + lr * 72 + 32 + lg * 8);
        }
        __builtin_amdgcn_s_setprio(1);
#pragma unroll
        for (int dt = 0; dt < 4; ++dt) {
            bf16x8 v0f = ldfrag(base + (8 + dt * 2) * 512 + lane * 8);
            bf16x8 v1f = ldfrag(base + (8 + dt * 2 + 1) * 512 + lane * 8);
#pragma unroll
            for (int s = 0; s < 2; ++s) {
                of[s][dt] = mfma16(pa[s][0], v0f, of[s][dt]);
                of[s][dt] = mfma16(pa[s][1], v1f, of[s][dt]);
            }
        }
        __builtin_amdgcn_s_setprio(0);
    };

    for (int t = 0; t < 8; ++t) {
        const int kv0 = t * 128;
#pragma unroll
        for (int q = 0; q < 8; ++q) {
            int st = wave * 8 + q;
            int chunk = st >> 4, r = st & 15;
            int kvb = kv0 + chunk * 64;
            const bf16* src;
            if (r < 8)
                src = kbase + (long)(kvb + (r >> 1) * 16 + lr) * 1536 +
                      (r & 1) * 32 + lg * 8;
            else {
                int vs = r - 8;
                src = vbase + (long)((vs >> 1) * 16 + lr) * 1024 + kvb +
                      (vs & 1) * 32 + lg * 8;
            }
            gload16(src, &sKV[st << 9]);
        }
        asm volatile("s_waitcnt vmcnt(0) lgkmcnt(0)" ::: "memory");
        __builtin_amdgcn_s_barrier();
        computeKV(&sKV[0]);
        computeKV(&sKV[8192]);
        __builtin_amdgcn_s_barrier();
    }

#pragma unroll
    for (int s = 0; s < 2; ++s) {
#pragma unroll
        for (int m = 1; m < 16; m <<= 1)
#pragma unroll
            for (int r = 0; r < 4; ++r)
                lrow[s][r] += __shfl_xor(lrow[s][r], m);
        bf16* op = o + ((long)b * 1024 + q0 + s * 16 + lg * 4) * 512 + h * 64 + lr;
#pragma unroll
        for (int r = 0; r < 4; ++r) {
            float inv = 1.f / lrow[s][r];
#pragma unroll
            for (int dt = 0; dt < 4; ++dt)
                op[(long)r * 512 + dt * 16] = __float2bfloat16(of[s][dt][r] * inv);
        }
    }
}

// ---------------------------------------------------------------- launcher
extern "C" void kernel_launch(void* const* d_in, const int* in_sizes, int n_in,
                              void* d_out, int out_size, void* d_ws, size_t ws_size,
                              hipStream_t stream) {
    const float* x = (const float*)d_in[0];
    const float* gn_g = (const float*)d_in[1];
    const float* gn_b = (const float*)d_in[2];
    const float* w_cin = (const float*)d_in[3];
    const float* b_cin = (const float*)d_in[4];
    const float* ln1_g = (const float*)d_in[5];
    const float* ln1_b = (const float*)d_in[6];
    const float* qkv1w = (const float*)d_in[7];
    const float* out1_w = (const float*)d_in[8];
    const float* out1_b = (const float*)d_in[9];
    const float* ln2_g = (const float*)d_in[10];
    const float* ln2_b = (const float*)d_in[11];
    const float* qkv2w = (const float*)d_in[12];
    const float* out2_w = (const float*)d_in[13];
    const float* out2_b = (const float*)d_in[14];
    const float* ln3_g = (const float*)d_in[15];
    const float* ln3_b = (const float*)d_in[16];
    const float* g1_w = (const float*)d_in[17];
    const float* g1_b = (const float*)d_in[18];
    const float* g2_w = (const float*)d_in[19];
    const float* g2_b = (const float*)d_in[20];
    const float* w_cout = (const float*)d_in[21];
    const float* b_cout = (const float*)d_in[22];
    float* out = (float*)d_out;

    char* ws = (char*)d_ws;
    float* stats = (float*)ws;
    bf16* wq1 = (bf16*)(ws + 4096);          // (1536,512)
    bf16* wo1 = wq1 + 1536 * 512;            // (512,512)
    bf16* wq2 = wo1 + 512 * 512;             // (1536,512)
    bf16* wo2 = wq2 + 1536 * 512;            // (512,512)
    bf16* wg1 = wo2 + 512 * 512;             // (4096,512)
    bf16* wg2 = wg1 + 4096 * 512;            // (512,2048)
    bf16* wci = wg2 + 512 * 2048;            // (512,512)
    bf16* wco = wci + 512 * 512;             // (512,512)
    bf16* h = wco + 512 * 512;               // (8192,512)
    bf16* h2 = h + (size_t)8192 * 512;
    bf16* lnb = h2 + (size_t)8192 * 512;     // xt / LN out / attn-O
    bf16* qkv = lnb + (size_t)8192 * 512;    // (8192,1536)
    bf16* obuf = qkv + (size_t)8192 * 1536;  // vt (B,H,64,S) during attn phases
    bf16* gg = qkv;                          // (8192,2048) reuses qkv+obuf
    bf16* vt = obuf;

    WJobs jobs;
    jobs.j[0] = {qkv1w, wq1, 512, 1536, 0, 1};
    jobs.j[1] = {out1_w, wo1, 512, 512, 768, 1};
    jobs.j[2] = {qkv2w, wq2, 512, 1536, 1024, 1};
    jobs.j[3] = {out2_w, wo2, 512, 512, 1792, 1};
    jobs.j[4] = {g1_w, wg1, 512, 4096, 2048, 1};
    jobs.j[5] = {g2_w, wg2, 2048, 512, 4096, 1};
    jobs.j[6] = {w_cin, wci, 512, 512, 5120, 0};
    jobs.j[7] = {w_cout, wco, 512, 512, 5376, 0};
    wconv_all<<<5632, 256, 0, stream>>>(jobs);

    gn_stats_k<<<256, 256, 0, stream>>>(x, stats);
    gnxt_k<<<dim3(16, 8, 8), 256, 0, stream>>>(x, stats, gn_g, gn_b, lnb);
    // conv_in: h = gn(x)^T @ wci^T
    mm_k<true, false, 64><<<dim3(8, 64), 256, 0, stream>>>(
        lnb, wci, b_cin, nullptr, h, 512, 512, 512, 8);

    ln_k<<<2048, 256, 0, stream>>>(h, ln1_g, ln1_b, lnb);
    mm256_k<false, false, true><<<dim3(32, 12), 512, 0, stream>>>(
        lnb, wq1, nullptr, nullptr, qkv, vt, 512, 512, 1536, 8);
    attn_mfma_k<<<dim3(8, 8, 8), 256, 0, stream>>>(qkv, vt, lnb);
    mm_k<true, true, 64><<<dim3(8, 64), 256, 0, stream>>>(
        lnb, wo1, out1_b, h, h2, 512, 512, 512, 8);

    ln_k<<<2048, 256, 0, stream>>>(h2, ln2_g, ln2_b, lnb);
    mm256_k<false, false, true><<<dim3(32, 12), 512, 0, stream>>>(
        lnb, wq2, nullptr, nullptr, qkv, vt, 512, 512, 1536, 8);
    attn_mfma_k<<<dim3(8, 8, 8), 256, 0, stream>>>(qkv, vt, lnb);
    mm_k<true, true, 64><<<dim3(8, 64), 256, 0, stream>>>(
        lnb, wo2, out2_b, h2, h, 512, 512, 512, 8);

    ln_k<<<2048, 256, 0, stream>>>(h, ln3_g, ln3_b, lnb);
    mm256_geglu_k<<<dim3(32, 32), 512, 0, stream>>>(
        lnb, wg1, wg1 + (size_t)2048 * 512, g1_b, gg, 8);
    mm_k<true, true, 64><<<dim3(8, 64), 256, 0, stream>>>(
        gg, wg2, g2_b, h, h2, 2048, 2048, 512, 32);

    // conv_out fused: out[b][o][s] = h2 @ wco^T + b_cout + x
    mm_convout_k<<<dim3(8, 64), 256, 0, stream>>>(
        h2, wco, b_cout, x, out, 8);
}